// Round 13
// baseline (257.672 us; speedup 1.0000x reference)
//
#include <hip/hip_runtime.h>
#include <math.h>

#define T_     4096
#define BH_    64
#define EPS_   1e-6f
#define SCALE_ 0.0625f   // 1/sqrt(256)

typedef _Float16 h16;
typedef __attribute__((ext_vector_type(4))) _Float16 h16x4;
typedef __attribute__((ext_vector_type(8))) _Float16 h16x8;
typedef __attribute__((ext_vector_type(4))) short    short4v;
typedef __attribute__((ext_vector_type(8))) short    bf16x8;
typedef __attribute__((ext_vector_type(4))) float    f32x4;
typedef __attribute__((ext_vector_type(4))) unsigned uint4v;

__device__ __forceinline__ void bfsplit(float x, short& h, short& l) {
    unsigned u = __float_as_uint(x) + 0x8000u;       // round-half-up to bf16
    unsigned hb = u & 0xffff0000u;
    h = (short)(u >> 16);
    float lf = x - __uint_as_float(hb);              // exact residual
    l = (short)(__float_as_uint(lf) >> 16);          // truncated residual
}
// pack bf16(a) (low) | bf16(b) (high), round-half-up; returns residual bit patterns
__device__ __forceinline__ unsigned pk_hi2(float a, float b, unsigned& ra, unsigned& rb) {
    unsigned ua = __float_as_uint(a) + 0x8000u;
    unsigned ub = __float_as_uint(b) + 0x8000u;
    ra = ua & 0xffff0000u; rb = ub & 0xffff0000u;
    return __builtin_amdgcn_perm(ub, ua, 0x07060302u);
}
__device__ __forceinline__ unsigned pk_tr2(float a, float b) {   // truncating pack
    return __builtin_amdgcn_perm(__float_as_uint(b), __float_as_uint(a), 0x07060302u);
}
__device__ __forceinline__ bf16x8 mkbf8(unsigned a, unsigned b, unsigned c, unsigned d) {
    uint4v t; t.x = a; t.y = b; t.z = c; t.w = d;
    return __builtin_bit_cast(bf16x8, t);
}

// ============================================================
// prep: W (64x256) -> MFMA-fragment-ordered f16 hi/lo planes wfg:
//   frag(r, w, q)[8] = W^T[r][w*32+q*4 .. +3] ++ W^T[r][w*32+16+q*4 .. +3]
//   hi plane at [0, 16384) h16, lo plane at +16384. (HW-validated r7.)
// ============================================================
__global__ __launch_bounds__(256)
void k_prep(const float* __restrict__ Wg, h16* __restrict__ wfg)
{
    int d = blockIdx.x;      // 0..63
    int r = threadIdx.x;     // 0..255
    float x = Wg[d * 256 + r];
    h16 hi = (h16)x;
    h16 lo = (h16)(x - (float)hi);
    int w = d >> 5, rem = d & 31;
    int half = rem >> 4, qq = (rem >> 2) & 3, i = rem & 3;
    int dst = (r * 8 + w * 4 + qq) * 8 + half * 4 + i;
    wfg[dst]         = hi;
    wfg[16384 + dst] = lo;
}

// ============================================================
// Stage 1 (round-10 best + norms-in-proj): 4-wave blocks, 64-t chunks,
// 2 barriers/chunk. Staging = v+mask ONLY (k read once, in proj; row
// norms computed there from the same fp32 values via shfl — no norm LDS).
// Wave rg owns r-strip [rg*64,+64): kva[4][4] private, direct global
// writes at block end. grid(split, BH). 2 indep blocks/CU desync.
// ============================================================
__global__ __launch_bounds__(256, 2)
void k_stage1(const float* __restrict__ kg, const float* __restrict__ vg,
              const float* __restrict__ mg, const h16* __restrict__ wfg,
              float* __restrict__ kv_part, float* __restrict__ ks_part, int nch)
{
    __shared__ __align__(16) char smem[18688];
    short* vTh   = (short*)smem;                    // [64 d][72] 9216 B
    short* vTl   = (short*)(smem + 9216);           // [64 d][72] 9216 B
    float* msk_l = (float*)(smem + 18432);          // [64]        256 B

    const int tid  = threadIdx.x;
    const int lane = tid & 63, l15 = lane & 15, q = lane >> 4;
    const int rg   = tid >> 6;                      // wave id = r-strip
    const int s = blockIdx.x, bh = blockIdx.y, b = bh >> 4;
    const long rowb = (long)bh * T_;

    f32x4 kva[4][4];
#pragma unroll
    for (int a = 0; a < 4; ++a)
#pragma unroll
        for (int c2 = 0; c2 < 4; ++c2) { f32x4 z4 = {0.f,0.f,0.f,0.f}; kva[a][c2] = z4; }
    float ksa[4] = {0.f, 0.f, 0.f, 0.f};

    const int tlv = tid & 63;      // staging: t row
    const int dq  = tid >> 6;      // staging: 16-d quarter

    for (int c = 0; c < nch; ++c) {
        const int t0 = (s * nch + c) * 64;
        __syncthreads();   // prev chunk's vT/msk consumers done

        // ---- stage v^T (mask-scaled, bf16 hi/lo) + mask; NO k read ----
        {
            const float mval = mg[b * T_ + t0 + tlv];
            const float* vrow = vg + (rowb + t0 + tlv) * 64 + dq * 16;
#pragma unroll
            for (int j = 0; j < 4; ++j) {
                float4 vv = *(const float4*)(vrow + j * 4);
                int d = dq * 16 + j * 4;
                short h, l;
                bfsplit(vv.x * mval, h, l); vTh[(d+0)*72 + tlv] = h; vTl[(d+0)*72 + tlv] = l;
                bfsplit(vv.y * mval, h, l); vTh[(d+1)*72 + tlv] = h; vTl[(d+1)*72 + tlv] = l;
                bfsplit(vv.z * mval, h, l); vTh[(d+2)*72 + tlv] = h; vTl[(d+2)*72 + tlv] = l;
                bfsplit(vv.w * mval, h, l); vTh[(d+3)*72 + tlv] = h; vTl[(d+3)*72 + tlv] = l;
            }
            if (tid < 64) msk_l[tid] = mval * SCALE_;
        }
        __syncthreads();   // publish vT/msk_l

        // ---- proj + norms: pr[m][n]; rows t = t0+m*16+{l15|4q+j}, cols r = rg*64+n*16+l15 ----
        f32x4 pr[4][4];
#pragma unroll
        for (int m = 0; m < 4; ++m)
#pragma unroll
            for (int n = 0; n < 4; ++n) { f32x4 z4 = {0.f,0.f,0.f,0.f}; pr[m][n] = z4; }
        float s2m[4] = {0.f, 0.f, 0.f, 0.f};

#pragma unroll
        for (int w = 0; w < 2; ++w) {   // 32-d K windows
            h16x8 ah[4], al[4];
#pragma unroll
            for (int m = 0; m < 4; ++m) {
                const float* arow = kg + (rowb + t0 + m * 16 + l15) * 64 + w * 32 + q * 4;
                float4 x0 = *(const float4*)arow;
                float4 x1 = *(const float4*)(arow + 16);
                s2m[m] += x0.x*x0.x + x0.y*x0.y + x0.z*x0.z + x0.w*x0.w
                        + x1.x*x1.x + x1.y*x1.y + x1.z*x1.z + x1.w*x1.w;
                h16x8 hv, lv;
                hv[0] = (h16)x0.x; hv[1] = (h16)x0.y; hv[2] = (h16)x0.z; hv[3] = (h16)x0.w;
                hv[4] = (h16)x1.x; hv[5] = (h16)x1.y; hv[6] = (h16)x1.z; hv[7] = (h16)x1.w;
                lv[0] = (h16)(x0.x - (float)hv[0]); lv[1] = (h16)(x0.y - (float)hv[1]);
                lv[2] = (h16)(x0.z - (float)hv[2]); lv[3] = (h16)(x0.w - (float)hv[3]);
                lv[4] = (h16)(x1.x - (float)hv[4]); lv[5] = (h16)(x1.y - (float)hv[5]);
                lv[6] = (h16)(x1.z - (float)hv[6]); lv[7] = (h16)(x1.w - (float)hv[7]);
                ah[m] = hv; al[m] = lv;
            }
            h16x8 wbh[4], wbl[4];
#pragma unroll
            for (int n = 0; n < 4; ++n) {
                int fb = ((rg * 64 + n * 16 + l15) * 8 + w * 4 + q) * 8;
                wbh[n] = *(const h16x8*)&wfg[fb];
                wbl[n] = *(const h16x8*)&wfg[16384 + fb];
            }
#pragma unroll
            for (int m = 0; m < 4; ++m)
#pragma unroll
                for (int n = 0; n < 4; ++n) {
                    pr[m][n] = __builtin_amdgcn_mfma_f32_16x16x32_f16(ah[m], wbh[n], pr[m][n], 0, 0, 0);
                    pr[m][n] = __builtin_amdgcn_mfma_f32_16x16x32_f16(ah[m], wbl[n], pr[m][n], 0, 0, 0);
                    pr[m][n] = __builtin_amdgcn_mfma_f32_16x16x32_f16(al[m], wbh[n], pr[m][n], 0, 0, 0);
                }
        }
        // finish row norms: full 64-d sum per (m, l15) after q-reduce
#pragma unroll
        for (int m = 0; m < 4; ++m) {
            float v2 = s2m[m];
            v2 += __shfl_xor(v2, 16);
            v2 += __shfl_xor(v2, 32);
            s2m[m] = 0.5f * v2;
        }

        // ---- per 32-t window: exp -> bf16 split A-frags -> kv MFMA ----
#pragma unroll
        for (int W = 0; W < 2; ++W) {
            const int m0 = 2 * W, m1 = 2 * W + 1;
            const int rb0 = m0 * 16 + q * 4;
            float4 nq0, nq1;
            nq0.x = __shfl(s2m[m0], q * 4 + 0); nq0.y = __shfl(s2m[m0], q * 4 + 1);
            nq0.z = __shfl(s2m[m0], q * 4 + 2); nq0.w = __shfl(s2m[m0], q * 4 + 3);
            nq1.x = __shfl(s2m[m1], q * 4 + 0); nq1.y = __shfl(s2m[m1], q * 4 + 1);
            nq1.z = __shfl(s2m[m1], q * 4 + 2); nq1.w = __shfl(s2m[m1], q * 4 + 3);
            float4 sm0 = *(const float4*)&msk_l[rb0];
            float4 sm1 = *(const float4*)&msk_l[rb0 + 16];
            bf16x8 afh[4], afl[4];
#pragma unroll
            for (int n = 0; n < 4; ++n) {
                float ee[8];
                ee[0] = __expf(pr[m0][n][0] - nq0.x) * sm0.x;
                ee[1] = __expf(pr[m0][n][1] - nq0.y) * sm0.y;
                ee[2] = __expf(pr[m0][n][2] - nq0.z) * sm0.z;
                ee[3] = __expf(pr[m0][n][3] - nq0.w) * sm0.w;
                ee[4] = __expf(pr[m1][n][0] - nq1.x) * sm1.x;
                ee[5] = __expf(pr[m1][n][1] - nq1.y) * sm1.y;
                ee[6] = __expf(pr[m1][n][2] - nq1.z) * sm1.z;
                ee[7] = __expf(pr[m1][n][3] - nq1.w) * sm1.w;
                ksa[n] += ee[0]+ee[1]+ee[2]+ee[3]+ee[4]+ee[5]+ee[6]+ee[7];
                unsigned r0,r1,r2,r3,r4,r5,r6,r7;
                unsigned h01 = pk_hi2(ee[0], ee[1], r0, r1);
                unsigned h23 = pk_hi2(ee[2], ee[3], r2, r3);
                unsigned h45 = pk_hi2(ee[4], ee[5], r4, r5);
                unsigned h67 = pk_hi2(ee[6], ee[7], r6, r7);
                unsigned l01 = pk_tr2(ee[0]-__uint_as_float(r0), ee[1]-__uint_as_float(r1));
                unsigned l23 = pk_tr2(ee[2]-__uint_as_float(r2), ee[3]-__uint_as_float(r3));
                unsigned l45 = pk_tr2(ee[4]-__uint_as_float(r4), ee[5]-__uint_as_float(r5));
                unsigned l67 = pk_tr2(ee[6]-__uint_as_float(r6), ee[7]-__uint_as_float(r7));
                afh[n] = mkbf8(h01, h23, h45, h67);
                afl[n] = mkbf8(l01, l23, l45, l67);
            }
            bf16x8 bvh[4], bvl[4];
#pragma unroll
            for (int nd = 0; nd < 4; ++nd) {
                int base = (nd * 16 + l15) * 72 + W * 32 + q * 4;
                short4v a0 = *(const short4v*)&vTh[base];
                short4v a1 = *(const short4v*)&vTh[base + 16];
                short4v b0 = *(const short4v*)&vTl[base];
                short4v b1 = *(const short4v*)&vTl[base + 16];
                bf16x8 hv, lv;
                hv[0]=a0.x; hv[1]=a0.y; hv[2]=a0.z; hv[3]=a0.w; hv[4]=a1.x; hv[5]=a1.y; hv[6]=a1.z; hv[7]=a1.w;
                lv[0]=b0.x; lv[1]=b0.y; lv[2]=b0.z; lv[3]=b0.w; lv[4]=b1.x; lv[5]=b1.y; lv[6]=b1.z; lv[7]=b1.w;
                bvh[nd] = hv; bvl[nd] = lv;
            }
#pragma unroll
            for (int n = 0; n < 4; ++n)
#pragma unroll
                for (int nd = 0; nd < 4; ++nd) {
                    kva[n][nd] = __builtin_amdgcn_mfma_f32_16x16x32_bf16(afh[n], bvh[nd], kva[n][nd], 0, 0, 0);
                    kva[n][nd] = __builtin_amdgcn_mfma_f32_16x16x32_bf16(afh[n], bvl[nd], kva[n][nd], 0, 0, 0);
                    kva[n][nd] = __builtin_amdgcn_mfma_f32_16x16x32_bf16(afl[n], bvh[nd], kva[n][nd], 0, 0, 0);
                }
        }
    }

    // ---- block end: direct global writes (no cross-wave reduce) ----
#pragma unroll
    for (int n = 0; n < 4; ++n) {      // ksum: sum over q (t-quadrants)
        float v = ksa[n];
        v += __shfl_xor(v, 16);
        v += __shfl_xor(v, 32);
        if (q == 0) ks_part[(long)(s * BH_ + bh) * 256 + rg * 64 + n * 16 + l15] = v;
    }
    {
        const long pb = (long)(s * BH_ + bh) * (256 * 64);
#pragma unroll
        for (int n = 0; n < 4; ++n)
#pragma unroll
            for (int nd = 0; nd < 4; ++nd)
#pragma unroll
                for (int j = 0; j < 4; ++j)
                    kv_part[pb + (long)(rg * 64 + n * 16 + q * 4 + j) * 64 + nd * 16 + l15] = kva[n][nd][j];
    }
}

// ============================================================
// Reduce: sum split partials; emit kv^T bf16 hi/lo [bh][pl][64 d][264 r]
// + ksum_f.  grid(8, BH), 256 thr — each block: 32 r-rows of one head.
// ============================================================
__global__ __launch_bounds__(256)
void k_reduce(const float* __restrict__ kvp, const float* __restrict__ ksp,
              short* __restrict__ kvt, float* __restrict__ ksf, int split)
{
    __shared__ __align__(16) float red2[32 * 68];
    const int tid = threadIdx.x, rq = blockIdx.x, bh = blockIdx.y;
    const long NKV4 = (long)BH_ * 256 * 64 / 4;
#pragma unroll
    for (int i = 0; i < 2; ++i) {
        int idx4 = i * 256 + tid;
        long g = (long)bh * 4096 + rq * 512 + idx4;
        float4 a = ((const float4*)kvp)[g];
        for (int p = 1; p < split; ++p) {
            float4 t = ((const float4*)kvp)[(long)p * NKV4 + g];
            a.x += t.x; a.y += t.y; a.z += t.z; a.w += t.w;
        }
        int flat = idx4 * 4;
        int rl = flat >> 6, d = flat & 63;
        *(float4*)&red2[rl * 68 + d] = a;
    }
    if (tid < 32) {
        float s = 0.f;
        for (int p = 0; p < split; ++p) s += ksp[(long)p * (BH_ * 256) + bh * 256 + rq * 32 + tid];
        ksf[bh * 256 + rq * 32 + tid] = s;
    }
    __syncthreads();
    short* dh = kvt + (long)bh * 33792;
    short* dl = dh + 16896;
#pragma unroll
    for (int i = 0; i < 8; ++i) {
        int flat = i * 256 + tid;
        int d = flat >> 5, rl = flat & 31;
        short h, l;
        bfsplit(red2[rl * 68 + d], h, l);
        dh[d * 264 + rq * 32 + rl] = h;
        dl[d * 264 + rq * 32 + rl] = l;
    }
}

// ============================================================
// Stage 2 (round-10, unchanged): 4-wave blocks, 64-t tiles. Wave rs owns
// r-strip; proj^T -> exp (+z) -> out -> cross-rs reduce -> divide.
// grid(64, BH).
// ============================================================
__global__ __launch_bounds__(256, 2)
void k_stage2(const float* __restrict__ qg, const h16* __restrict__ wfg,
              const short* __restrict__ kvt, const float* __restrict__ ksf,
              float* __restrict__ outg)
{
    __shared__ __align__(16) char smem[69632];
    short* kvTh   = (short*)smem;                   // [64*264] 33792 B
    short* kvTl   = (short*)(smem + 33792);         // [64*264] 33792 B
    float* ksum_l = (float*)(smem + 67584);         // [256]     1024 B
    float* zb     = (float*)(smem + 68608);         // [4][64]   1024 B
    float* red    = (float*)smem;                   // alias kvTh: 64*68*4 = 17408 B

    const int tid  = threadIdx.x;
    const int lane = tid & 63, l15 = lane & 15, q = lane >> 4;
    const int rs   = tid >> 6;                      // wave id = r-strip
    const int bh = blockIdx.y, t0 = blockIdx.x * 64;
    const long rowb = (long)bh * T_;

    {
        const float4* s2p = (const float4*)(kvt + (long)bh * 33792);
        float4* d2 = (float4*)kvTh;
#pragma unroll
        for (int i = 0; i < 17; ++i) { int idx = i * 256 + tid; if (idx < 4224) d2[idx] = s2p[idx]; }
        ksum_l[tid] = ksf[bh * 256 + tid];
    }
    __syncthreads();

    // ---- proj^T: rows r = rs*64+m*16+{l15|4q+j}, cols t = t0+n*16+l15 ----
    f32x4 pr[4][4];
#pragma unroll
    for (int m = 0; m < 4; ++m)
#pragma unroll
        for (int n = 0; n < 4; ++n) { f32x4 z4 = {0.f,0.f,0.f,0.f}; pr[m][n] = z4; }
    float nacc[4] = {0.f, 0.f, 0.f, 0.f};

#pragma unroll
    for (int w = 0; w < 2; ++w) {
        h16x8 aWh[4], aWl[4];
#pragma unroll
        for (int m = 0; m < 4; ++m) {
            int fb = ((rs * 64 + m * 16 + l15) * 8 + w * 4 + q) * 8;
            aWh[m] = *(const h16x8*)&wfg[fb];
            aWl[m] = *(const h16x8*)&wfg[16384 + fb];
        }
        h16x8 qbh[4], qbl[4];
#pragma unroll
        for (int n = 0; n < 4; ++n) {
            const float* qrow = qg + (rowb + t0 + n * 16 + l15) * 64 + w * 32 + q * 4;
            float4 x0 = *(const float4*)qrow;
            float4 x1 = *(const float4*)(qrow + 16);
            nacc[n] += x0.x * x0.x + x0.y * x0.y + x0.z * x0.z + x0.w * x0.w
                     + x1.x * x1.x + x1.y * x1.y + x1.z * x1.z + x1.w * x1.w;
            h16x8 hv, lv;
            hv[0] = (h16)x0.x; hv[1] = (h16)x0.y; hv[2] = (h16)x0.z; hv[3] = (h16)x0.w;
            hv[4] = (h16)x1.x; hv[5] = (h16)x1.y; hv[6] = (h16)x1.z; hv[7] = (h16)x1.w;
            lv[0] = (h16)(x0.x - (float)hv[0]); lv[1] = (h16)(x0.y - (float)hv[1]);
            lv[2] = (h16)(x0.z - (float)hv[2]); lv[3] = (h16)(x0.w - (float)hv[3]);
            lv[4] = (h16)(x1.x - (float)hv[4]); lv[5] = (h16)(x1.y - (float)hv[5]);
            lv[6] = (h16)(x1.z - (float)hv[6]); lv[7] = (h16)(x1.w - (float)hv[7]);
            qbh[n] = hv; qbl[n] = lv;
        }
#pragma unroll
        for (int m = 0; m < 4; ++m)
#pragma unroll
            for (int n = 0; n < 4; ++n) {
                pr[m][n] = __builtin_amdgcn_mfma_f32_16x16x32_f16(aWh[m], qbh[n], pr[m][n], 0, 0, 0);
                pr[m][n] = __builtin_amdgcn_mfma_f32_16x16x32_f16(aWh[m], qbl[n], pr[m][n], 0, 0, 0);
                pr[m][n] = __builtin_amdgcn_mfma_f32_16x16x32_f16(aWl[m], qbh[n], pr[m][n], 0, 0, 0);
            }
    }
    float normt[4];
#pragma unroll
    for (int n = 0; n < 4; ++n) {
        float v = nacc[n];
        v += __shfl_xor(v, 16);
        v += __shfl_xor(v, 32);
        normt[n] = 0.5f * v;
    }

    // ---- exp + z + out-GEMM per 32-r window ----
    f32x4 oac[4][4];
#pragma unroll
    for (int n = 0; n < 4; ++n)
#pragma unroll
        for (int nd = 0; nd < 4; ++nd) { f32x4 z4 = {0.f,0.f,0.f,0.f}; oac[n][nd] = z4; }
    float zp[4] = {0.f, 0.f, 0.f, 0.f};

#pragma unroll
    for (int W = 0; W < 2; ++W) {
        bf16x8 aph[4], apl[4];
#pragma unroll
        for (int n = 0; n < 4; ++n) {
            float ee[8];
#pragma unroll
            for (int half = 0; half < 2; ++half) {
                int m = 2 * W + half;
                int rl = rs * 64 + m * 16 + q * 4;
#pragma unroll
                for (int j = 0; j < 4; ++j) {
                    float e = __expf(pr[m][n][j] - normt[n]) * SCALE_;
                    zp[n] += e * ksum_l[rl + j];
                    ee[half * 4 + j] = e;
                }
            }
            unsigned r0,r1,r2,r3,r4,r5,r6,r7;
            unsigned h01 = pk_hi2(ee[0], ee[1], r0, r1);
            unsigned h23 = pk_hi2(ee[2], ee[3], r2, r3);
            unsigned h45 = pk_hi2(ee[4], ee[5], r4, r5);
            unsigned h67 = pk_hi2(ee[6], ee[7], r6, r7);
            unsigned l01 = pk_tr2(ee[0]-__uint_as_float(r0), ee[1]-__uint_as_float(r1));
            unsigned l23 = pk_tr2(ee[2]-__uint_as_float(r2), ee[3]-__uint_as_float(r3));
            unsigned l45 = pk_tr2(ee[4]-__uint_as_float(r4), ee[5]-__uint_as_float(r5));
            unsigned l67 = pk_tr2(ee[6]-__uint_as_float(r6), ee[7]-__uint_as_float(r7));
            aph[n] = mkbf8(h01, h23, h45, h67);
            apl[n] = mkbf8(l01, l23, l45, l67);
        }
        bf16x8 bkh[4], bkl[4];
#pragma unroll
        for (int nd = 0; nd < 4; ++nd) {
            int d  = nd * 16 + l15;
            int rb = rs * 64 + W * 32 + q * 4;
            short4v a0 = *(const short4v*)&kvTh[d * 264 + rb];
            short4v a1 = *(const short4v*)&kvTh[d * 264 + rb + 16];
            short4v b0 = *(const short4v*)&kvTl[d * 264 + rb];
            short4v b1 = *(const short4v*)&kvTl[d * 264 + rb + 16];
            bf16x8 hv, lv;
            hv[0]=a0.x; hv[1]=a0.y; hv[2]=a0.z; hv[3]=a0.w; hv[4]=a1.x; hv[5]=a1.y; hv[6]=a1.z; hv[7]=a1.w;
            lv[0]=b0.x; lv[1]=b0.y; lv[2]=b0.z; lv[3]=b0.w; lv[4]=b1.x; lv[5]=b1.y; lv[6]=b1.z; lv[7]=b1.w;
            bkh[nd] = hv; bkl[nd] = lv;
        }
#pragma unroll
        for (int n = 0; n < 4; ++n)
#pragma unroll
            for (int nd = 0; nd < 4; ++nd) {
                oac[n][nd] = __builtin_amdgcn_mfma_f32_16x16x32_bf16(aph[n], bkh[nd], oac[n][nd], 0, 0, 0);
                oac[n][nd] = __builtin_amdgcn_mfma_f32_16x16x32_bf16(aph[n], bkl[nd], oac[n][nd], 0, 0, 0);
                oac[n][nd] = __builtin_amdgcn_mfma_f32_16x16x32_bf16(apl[n], bkh[nd], oac[n][nd], 0, 0, 0);
            }
    }
#pragma unroll
    for (int n = 0; n < 4; ++n) {   // z partials (sum over r-quadrants)
        float v = zp[n];
        v += __shfl_xor(v, 16);
        v += __shfl_xor(v, 32);
        if (q == 0) zb[rs * 64 + n * 16 + l15] = v;
    }
    __syncthreads();   // all kvT reads done -> red (alias) writable; zb visible

    // ---- sequential reduce over r-strips into red ----
#pragma unroll
    for (int p = 0; p < 4; ++p) {
        if (rs == p) {
#pragma unroll
            for (int n = 0; n < 4; ++n)
#pragma unroll
                for (int nd = 0; nd < 4; ++nd)
#pragma unroll
                    for (int j = 0; j < 4; ++j) {
                        int idx = (n * 16 + q * 4 + j) * 68 + nd * 16 + l15;
                        if (p == 0) red[idx] = oac[n][nd][j];
                        else        red[idx] += oac[n][nd][j];
                    }
        }
        __syncthreads();
    }

    // ---- epilogue: divide by z+eps, store ----
#pragma unroll
    for (int i = 0; i < 4; ++i) {
        int flat = i * 1024 + tid * 4;
        int tl = flat >> 6, d = flat & 63;
        float z = zb[tl] + zb[64 + tl] + zb[128 + tl] + zb[192 + tl] + EPS_;
        float rz = 1.f / z;
        float4 o = *(const float4*)&red[tl * 68 + d];
        o.x *= rz; o.y *= rz; o.z *= rz; o.w *= rz;
        *(float4*)&outg[(rowb + t0 + tl) * 64 + d] = o;
    }
}

// ============================================================
extern "C" void kernel_launch(void* const* d_in, const int* in_sizes, int n_in,
                              void* d_out, int out_size, void* d_ws, size_t ws_size,
                              hipStream_t stream)
{
    const float* q  = (const float*)d_in[0];
    const float* k  = (const float*)d_in[1];
    const float* v  = (const float*)d_in[2];
    const float* m  = (const float*)d_in[3];
    const float* W  = (const float*)d_in[4];
    float* out = (float*)d_out;

    char* ws = (char*)d_ws;
    h16*   wfg = (h16*)ws;                                   // 65536 B
    short* kvt = (short*)(ws + 65536);                       // 4325376 B
    float* ksf = (float*)(ws + 65536 + 4325376);             // 65536 B

    int split = 8;
    while (split > 1) {
        size_t need = 65536ull + 4325376ull + 65536ull
                    + (size_t)split * (4194304ull + 65536ull);
        if (need <= ws_size) break;
        split >>= 1;
    }
    float* kvp = (float*)(ws + 65536 + 4325376 + 65536);
    float* ksp = kvp + (size_t)split * (256 * 64 * BH_);
    int nch = (T_ / split) / 64;

    k_prep  <<<dim3(64),           dim3(256), 0, stream>>>(W, wfg);
    k_stage1<<<dim3(split, BH_),   dim3(256), 0, stream>>>(k, v, m, wfg, kvp, ksp, nch);
    k_reduce<<<dim3(8, BH_),       dim3(256), 0, stream>>>(kvp, ksp, kvt, ksf, split);
    k_stage2<<<dim3(T_ / 64, BH_), dim3(256), 0, stream>>>(q, wfg, kvt, ksf, out);
}

// Round 14
// 248.210 us; speedup vs baseline: 1.0381x; 1.0381x over previous
//
#include <hip/hip_runtime.h>
#include <math.h>

#define T_     4096
#define BH_    64
#define EPS_   1e-6f
#define SCALE_ 0.0625f   // 1/sqrt(256)

typedef _Float16 h16;
typedef __attribute__((ext_vector_type(4))) _Float16 h16x4;
typedef __attribute__((ext_vector_type(8))) _Float16 h16x8;
typedef __attribute__((ext_vector_type(4))) short    short4v;
typedef __attribute__((ext_vector_type(8))) short    bf16x8;
typedef __attribute__((ext_vector_type(4))) float    f32x4;
typedef __attribute__((ext_vector_type(4))) unsigned uint4v;

__device__ __forceinline__ void bfsplit(float x, short& h, short& l) {
    unsigned u = __float_as_uint(x) + 0x8000u;       // round-half-up to bf16
    unsigned hb = u & 0xffff0000u;
    h = (short)(u >> 16);
    float lf = x - __uint_as_float(hb);              // exact residual
    l = (short)(__float_as_uint(lf) >> 16);          // truncated residual
}
// pack bf16(a) (low) | bf16(b) (high), round-half-up; returns residual bit patterns
__device__ __forceinline__ unsigned pk_hi2(float a, float b, unsigned& ra, unsigned& rb) {
    unsigned ua = __float_as_uint(a) + 0x8000u;
    unsigned ub = __float_as_uint(b) + 0x8000u;
    ra = ua & 0xffff0000u; rb = ub & 0xffff0000u;
    return __builtin_amdgcn_perm(ub, ua, 0x07060302u);
}
__device__ __forceinline__ unsigned pk_tr2(float a, float b) {   // truncating pack
    return __builtin_amdgcn_perm(__float_as_uint(b), __float_as_uint(a), 0x07060302u);
}
__device__ __forceinline__ bf16x8 mkbf8(unsigned a, unsigned b, unsigned c, unsigned d) {
    uint4v t; t.x = a; t.y = b; t.z = c; t.w = d;
    return __builtin_bit_cast(bf16x8, t);
}

// ============================================================
// prep: W (64x256) -> MFMA-fragment-ordered f16 hi/lo planes wfg:
//   frag(r, w, q)[8] = W^T[r][w*32+q*4 .. +3] ++ W^T[r][w*32+16+q*4 .. +3]
//   hi plane at [0, 16384) h16, lo plane at +16384. (HW-validated r7.)
// ============================================================
__global__ __launch_bounds__(256)
void k_prep(const float* __restrict__ Wg, h16* __restrict__ wfg)
{
    int d = blockIdx.x;      // 0..63
    int r = threadIdx.x;     // 0..255
    float x = Wg[d * 256 + r];
    h16 hi = (h16)x;
    h16 lo = (h16)(x - (float)hi);
    int w = d >> 5, rem = d & 31;
    int half = rem >> 4, qq = (rem >> 2) & 3, i = rem & 3;
    int dst = (r * 8 + w * 4 + qq) * 8 + half * 4 + i;
    wfg[dst]         = hi;
    wfg[16384 + dst] = lo;
}

// ============================================================
// Stage 1 (measured-best, round 10): 4-wave blocks (256 thr), 64-t
// chunks. Wave rg owns r-strip [rg*64,+64) fully: proj (f16x3) -> exp
// -> kv (bf16x3) accumulated over all t — NO cross-wave reduce.
// 2 indep blocks/CU (desync barriers). grid(split, BH).
// ============================================================
__global__ __launch_bounds__(256, 2)
void k_stage1(const float* __restrict__ kg, const float* __restrict__ vg,
              const float* __restrict__ mg, const h16* __restrict__ wfg,
              float* __restrict__ kv_part, float* __restrict__ ks_part, int nch)
{
    __shared__ __align__(16) char smem[19968];
    short* vTh    = (short*)smem;                   // [64 d][72] 9216 B
    short* vTl    = (short*)(smem + 9216);          // [64 d][72] 9216 B
    float* np     = (float*)(smem + 18432);         // [4][64]    1024 B
    float* norm_l = (float*)(smem + 19456);         // [64]        256 B
    float* msk_l  = (float*)(smem + 19712);         // [64]        256 B

    const int tid  = threadIdx.x;
    const int lane = tid & 63, l15 = lane & 15, q = lane >> 4;
    const int rg   = tid >> 6;                      // wave id = r-strip
    const int s = blockIdx.x, bh = blockIdx.y, b = bh >> 4;
    const long rowb = (long)bh * T_;

    f32x4 kva[4][4];
#pragma unroll
    for (int a = 0; a < 4; ++a)
#pragma unroll
        for (int c2 = 0; c2 < 4; ++c2) { f32x4 z4 = {0.f,0.f,0.f,0.f}; kva[a][c2] = z4; }
    float ksa[4] = {0.f, 0.f, 0.f, 0.f};

    const int tlv = tid & 63;      // staging: t row
    const int dq  = tid >> 6;      // staging: 16-d quarter

    for (int c = 0; c < nch; ++c) {
        const int t0 = (s * nch + c) * 64;
        __syncthreads();   // prev chunk's vT consumers done

        // ---- stage v^T (mask-scaled, bf16 hi/lo) + k row-norm partials ----
        {
            const float mval = mg[b * T_ + t0 + tlv];
            const float* vrow = vg + (rowb + t0 + tlv) * 64 + dq * 16;
            const float* krow = kg + (rowb + t0 + tlv) * 64 + dq * 16;
            float s2 = 0.f;
#pragma unroll
            for (int j = 0; j < 4; ++j) {
                float4 vv = *(const float4*)(vrow + j * 4);
                float4 kk = *(const float4*)(krow + j * 4);
                s2 += kk.x * kk.x + kk.y * kk.y + kk.z * kk.z + kk.w * kk.w;
                float xs[4] = {vv.x * mval, vv.y * mval, vv.z * mval, vv.w * mval};
#pragma unroll
                for (int e = 0; e < 4; ++e) {
                    int d = dq * 16 + j * 4 + e;
                    short hi, lo;
                    bfsplit(xs[e], hi, lo);
                    vTh[d * 72 + tlv] = hi;
                    vTl[d * 72 + tlv] = lo;
                }
            }
            np[dq * 64 + tlv] = s2;
        }
        __syncthreads();   // staging visible
        if (tid < 64) {    // norm pass (read in exp phase, after next barrier)
            norm_l[tid] = 0.5f * (np[tid] + np[64 + tid] + np[128 + tid] + np[192 + tid]);
            msk_l[tid]  = mg[b * T_ + t0 + tid] * SCALE_;
        }

        // ---- proj: pr[m][n]; rows t = t0+m*16+{l15|4q+j}, cols r = rg*64+n*16+l15 ----
        f32x4 pr[4][4];
#pragma unroll
        for (int m = 0; m < 4; ++m)
#pragma unroll
            for (int n = 0; n < 4; ++n) { f32x4 z4 = {0.f,0.f,0.f,0.f}; pr[m][n] = z4; }

#pragma unroll
        for (int w = 0; w < 2; ++w) {   // 32-d K windows
            h16x8 ah[4], al[4];
#pragma unroll
            for (int m = 0; m < 4; ++m) {
                const float* arow = kg + (rowb + t0 + m * 16 + l15) * 64 + w * 32 + q * 4;
                float4 x0 = *(const float4*)arow;
                float4 x1 = *(const float4*)(arow + 16);
                h16x8 hv, lv;
                hv[0] = (h16)x0.x; hv[1] = (h16)x0.y; hv[2] = (h16)x0.z; hv[3] = (h16)x0.w;
                hv[4] = (h16)x1.x; hv[5] = (h16)x1.y; hv[6] = (h16)x1.z; hv[7] = (h16)x1.w;
                lv[0] = (h16)(x0.x - (float)hv[0]); lv[1] = (h16)(x0.y - (float)hv[1]);
                lv[2] = (h16)(x0.z - (float)hv[2]); lv[3] = (h16)(x0.w - (float)hv[3]);
                lv[4] = (h16)(x1.x - (float)hv[4]); lv[5] = (h16)(x1.y - (float)hv[5]);
                lv[6] = (h16)(x1.z - (float)hv[6]); lv[7] = (h16)(x1.w - (float)hv[7]);
                ah[m] = hv; al[m] = lv;
            }
            h16x8 wbh[4], wbl[4];
#pragma unroll
            for (int n = 0; n < 4; ++n) {
                int fb = ((rg * 64 + n * 16 + l15) * 8 + w * 4 + q) * 8;
                wbh[n] = *(const h16x8*)&wfg[fb];
                wbl[n] = *(const h16x8*)&wfg[16384 + fb];
            }
#pragma unroll
            for (int m = 0; m < 4; ++m)
#pragma unroll
                for (int n = 0; n < 4; ++n) {
                    pr[m][n] = __builtin_amdgcn_mfma_f32_16x16x32_f16(ah[m], wbh[n], pr[m][n], 0, 0, 0);
                    pr[m][n] = __builtin_amdgcn_mfma_f32_16x16x32_f16(ah[m], wbl[n], pr[m][n], 0, 0, 0);
                    pr[m][n] = __builtin_amdgcn_mfma_f32_16x16x32_f16(al[m], wbh[n], pr[m][n], 0, 0, 0);
                }
        }
        __syncthreads();   // norm_l/msk_l visible to all waves

        // ---- per 32-t window: exp -> bf16 split A-frags -> kv MFMA ----
#pragma unroll
        for (int W = 0; W < 2; ++W) {
            const int m0 = 2 * W, m1 = 2 * W + 1;
            const int rb0 = m0 * 16 + q * 4;
            float4 nq0 = *(const float4*)&norm_l[rb0];
            float4 nq1 = *(const float4*)&norm_l[rb0 + 16];
            float4 sm0 = *(const float4*)&msk_l[rb0];
            float4 sm1 = *(const float4*)&msk_l[rb0 + 16];
            bf16x8 afh[4], afl[4];
#pragma unroll
            for (int n = 0; n < 4; ++n) {
                float ee[8];
                ee[0] = __expf(pr[m0][n][0] - nq0.x) * sm0.x;
                ee[1] = __expf(pr[m0][n][1] - nq0.y) * sm0.y;
                ee[2] = __expf(pr[m0][n][2] - nq0.z) * sm0.z;
                ee[3] = __expf(pr[m0][n][3] - nq0.w) * sm0.w;
                ee[4] = __expf(pr[m1][n][0] - nq1.x) * sm1.x;
                ee[5] = __expf(pr[m1][n][1] - nq1.y) * sm1.y;
                ee[6] = __expf(pr[m1][n][2] - nq1.z) * sm1.z;
                ee[7] = __expf(pr[m1][n][3] - nq1.w) * sm1.w;
                ksa[n] += ee[0]+ee[1]+ee[2]+ee[3]+ee[4]+ee[5]+ee[6]+ee[7];
                unsigned r0,r1,r2,r3,r4,r5,r6,r7;
                unsigned h01 = pk_hi2(ee[0], ee[1], r0, r1);
                unsigned h23 = pk_hi2(ee[2], ee[3], r2, r3);
                unsigned h45 = pk_hi2(ee[4], ee[5], r4, r5);
                unsigned h67 = pk_hi2(ee[6], ee[7], r6, r7);
                unsigned l01 = pk_tr2(ee[0]-__uint_as_float(r0), ee[1]-__uint_as_float(r1));
                unsigned l23 = pk_tr2(ee[2]-__uint_as_float(r2), ee[3]-__uint_as_float(r3));
                unsigned l45 = pk_tr2(ee[4]-__uint_as_float(r4), ee[5]-__uint_as_float(r5));
                unsigned l67 = pk_tr2(ee[6]-__uint_as_float(r6), ee[7]-__uint_as_float(r7));
                afh[n] = mkbf8(h01, h23, h45, h67);
                afl[n] = mkbf8(l01, l23, l45, l67);
            }
            bf16x8 bvh[4], bvl[4];
#pragma unroll
            for (int nd = 0; nd < 4; ++nd) {
                int base = (nd * 16 + l15) * 72 + W * 32 + q * 4;
                short4v a0 = *(const short4v*)&vTh[base];
                short4v a1 = *(const short4v*)&vTh[base + 16];
                short4v b0 = *(const short4v*)&vTl[base];
                short4v b1 = *(const short4v*)&vTl[base + 16];
                bf16x8 hv, lv;
                hv[0]=a0.x; hv[1]=a0.y; hv[2]=a0.z; hv[3]=a0.w; hv[4]=a1.x; hv[5]=a1.y; hv[6]=a1.z; hv[7]=a1.w;
                lv[0]=b0.x; lv[1]=b0.y; lv[2]=b0.z; lv[3]=b0.w; lv[4]=b1.x; lv[5]=b1.y; lv[6]=b1.z; lv[7]=b1.w;
                bvh[nd] = hv; bvl[nd] = lv;
            }
#pragma unroll
            for (int n = 0; n < 4; ++n)
#pragma unroll
                for (int nd = 0; nd < 4; ++nd) {
                    kva[n][nd] = __builtin_amdgcn_mfma_f32_16x16x32_bf16(afh[n], bvh[nd], kva[n][nd], 0, 0, 0);
                    kva[n][nd] = __builtin_amdgcn_mfma_f32_16x16x32_bf16(afh[n], bvl[nd], kva[n][nd], 0, 0, 0);
                    kva[n][nd] = __builtin_amdgcn_mfma_f32_16x16x32_bf16(afl[n], bvh[nd], kva[n][nd], 0, 0, 0);
                }
        }
    }

    // ---- block end: direct global writes (no cross-wave reduce) ----
#pragma unroll
    for (int n = 0; n < 4; ++n) {      // ksum: sum over q (t-quadrants)
        float v = ksa[n];
        v += __shfl_xor(v, 16);
        v += __shfl_xor(v, 32);
        if (q == 0) ks_part[(long)(s * BH_ + bh) * 256 + rg * 64 + n * 16 + l15] = v;
    }
    {
        const long pb = (long)(s * BH_ + bh) * (256 * 64);
#pragma unroll
        for (int n = 0; n < 4; ++n)
#pragma unroll
            for (int nd = 0; nd < 4; ++nd)
#pragma unroll
                for (int j = 0; j < 4; ++j)
                    kv_part[pb + (long)(rg * 64 + n * 16 + q * 4 + j) * 64 + nd * 16 + l15] = kva[n][nd][j];
    }
}

// ============================================================
// Reduce: sum split partials; emit kv^T bf16 hi/lo [bh][pl][64 d][264 r]
// + ksum_f.  grid(8, BH), 256 thr — each block: 32 r-rows of one head.
// ============================================================
__global__ __launch_bounds__(256)
void k_reduce(const float* __restrict__ kvp, const float* __restrict__ ksp,
              short* __restrict__ kvt, float* __restrict__ ksf, int split)
{
    __shared__ __align__(16) float red2[32 * 68];
    const int tid = threadIdx.x, rq = blockIdx.x, bh = blockIdx.y;
    const long NKV4 = (long)BH_ * 256 * 64 / 4;
#pragma unroll
    for (int i = 0; i < 2; ++i) {
        int idx4 = i * 256 + tid;
        long g = (long)bh * 4096 + rq * 512 + idx4;
        float4 a = ((const float4*)kvp)[g];
        for (int p = 1; p < split; ++p) {
            float4 t = ((const float4*)kvp)[(long)p * NKV4 + g];
            a.x += t.x; a.y += t.y; a.z += t.z; a.w += t.w;
        }
        int flat = idx4 * 4;
        int rl = flat >> 6, d = flat & 63;
        *(float4*)&red2[rl * 68 + d] = a;
    }
    if (tid < 32) {
        float s = 0.f;
        for (int p = 0; p < split; ++p) s += ksp[(long)p * (BH_ * 256) + bh * 256 + rq * 32 + tid];
        ksf[bh * 256 + rq * 32 + tid] = s;
    }
    __syncthreads();
    short* dh = kvt + (long)bh * 33792;
    short* dl = dh + 16896;
#pragma unroll
    for (int i = 0; i < 8; ++i) {
        int flat = i * 256 + tid;
        int d = flat >> 5, rl = flat & 31;
        short h, l;
        bfsplit(red2[rl * 68 + d], h, l);
        dh[d * 264 + rq * 32 + rl] = h;
        dl[d * 264 + rq * 32 + rl] = l;
    }
}

// ============================================================
// Stage 2 (measured-best, round 10): 4-wave blocks (256 thr), 64-t tiles.
// Wave rs owns r-strip; proj^T (f16x3) -> exp (+z) -> out (bf16x3) ->
// cross-rs reduce (red aliases dead kvT) -> divide. 2 indep blocks/CU.
// grid(64, BH).
// ============================================================
__global__ __launch_bounds__(256, 2)
void k_stage2(const float* __restrict__ qg, const h16* __restrict__ wfg,
              const short* __restrict__ kvt, const float* __restrict__ ksf,
              float* __restrict__ outg)
{
    __shared__ __align__(16) char smem[69632];
    short* kvTh   = (short*)smem;                   // [64*264] 33792 B
    short* kvTl   = (short*)(smem + 33792);         // [64*264] 33792 B
    float* ksum_l = (float*)(smem + 67584);         // [256]     1024 B
    float* zb     = (float*)(smem + 68608);         // [4][64]   1024 B
    float* red    = (float*)smem;                   // alias kvTh: 64*68*4 = 17408 B

    const int tid  = threadIdx.x;
    const int lane = tid & 63, l15 = lane & 15, q = lane >> 4;
    const int rs   = tid >> 6;                      // wave id = r-strip
    const int bh = blockIdx.y, t0 = blockIdx.x * 64;
    const long rowb = (long)bh * T_;

    {
        const float4* s2p = (const float4*)(kvt + (long)bh * 33792);
        float4* d2 = (float4*)kvTh;
#pragma unroll
        for (int i = 0; i < 17; ++i) { int idx = i * 256 + tid; if (idx < 4224) d2[idx] = s2p[idx]; }
        ksum_l[tid] = ksf[bh * 256 + tid];
    }
    __syncthreads();

    // ---- proj^T: rows r = rs*64+m*16+{l15|4q+j}, cols t = t0+n*16+l15 ----
    f32x4 pr[4][4];
#pragma unroll
    for (int m = 0; m < 4; ++m)
#pragma unroll
        for (int n = 0; n < 4; ++n) { f32x4 z4 = {0.f,0.f,0.f,0.f}; pr[m][n] = z4; }
    float nacc[4] = {0.f, 0.f, 0.f, 0.f};

#pragma unroll
    for (int w = 0; w < 2; ++w) {
        h16x8 aWh[4], aWl[4];
#pragma unroll
        for (int m = 0; m < 4; ++m) {
            int fb = ((rs * 64 + m * 16 + l15) * 8 + w * 4 + q) * 8;
            aWh[m] = *(const h16x8*)&wfg[fb];
            aWl[m] = *(const h16x8*)&wfg[16384 + fb];
        }
        h16x8 qbh[4], qbl[4];
#pragma unroll
        for (int n = 0; n < 4; ++n) {
            const float* qrow = qg + (rowb + t0 + n * 16 + l15) * 64 + w * 32 + q * 4;
            float4 x0 = *(const float4*)qrow;
            float4 x1 = *(const float4*)(qrow + 16);
            nacc[n] += x0.x * x0.x + x0.y * x0.y + x0.z * x0.z + x0.w * x0.w
                     + x1.x * x1.x + x1.y * x1.y + x1.z * x1.z + x1.w * x1.w;
            h16x8 hv, lv;
            hv[0] = (h16)x0.x; hv[1] = (h16)x0.y; hv[2] = (h16)x0.z; hv[3] = (h16)x0.w;
            hv[4] = (h16)x1.x; hv[5] = (h16)x1.y; hv[6] = (h16)x1.z; hv[7] = (h16)x1.w;
            lv[0] = (h16)(x0.x - (float)hv[0]); lv[1] = (h16)(x0.y - (float)hv[1]);
            lv[2] = (h16)(x0.z - (float)hv[2]); lv[3] = (h16)(x0.w - (float)hv[3]);
            lv[4] = (h16)(x1.x - (float)hv[4]); lv[5] = (h16)(x1.y - (float)hv[5]);
            lv[6] = (h16)(x1.z - (float)hv[6]); lv[7] = (h16)(x1.w - (float)hv[7]);
            qbh[n] = hv; qbl[n] = lv;
        }
#pragma unroll
        for (int m = 0; m < 4; ++m)
#pragma unroll
            for (int n = 0; n < 4; ++n) {
                pr[m][n] = __builtin_amdgcn_mfma_f32_16x16x32_f16(aWh[m], qbh[n], pr[m][n], 0, 0, 0);
                pr[m][n] = __builtin_amdgcn_mfma_f32_16x16x32_f16(aWh[m], qbl[n], pr[m][n], 0, 0, 0);
                pr[m][n] = __builtin_amdgcn_mfma_f32_16x16x32_f16(aWl[m], qbh[n], pr[m][n], 0, 0, 0);
            }
    }
    float normt[4];
#pragma unroll
    for (int n = 0; n < 4; ++n) {
        float v = nacc[n];
        v += __shfl_xor(v, 16);
        v += __shfl_xor(v, 32);
        normt[n] = 0.5f * v;
    }

    // ---- exp + z + out-GEMM per 32-r window ----
    f32x4 oac[4][4];
#pragma unroll
    for (int n = 0; n < 4; ++n)
#pragma unroll
        for (int nd = 0; nd < 4; ++nd) { f32x4 z4 = {0.f,0.f,0.f,0.f}; oac[n][nd] = z4; }
    float zp[4] = {0.f, 0.f, 0.f, 0.f};

#pragma unroll
    for (int W = 0; W < 2; ++W) {
        bf16x8 aph[4], apl[4];
#pragma unroll
        for (int n = 0; n < 4; ++n) {
            float ee[8];
#pragma unroll
            for (int half = 0; half < 2; ++half) {
                int m = 2 * W + half;
                int rl = rs * 64 + m * 16 + q * 4;
#pragma unroll
                for (int j = 0; j < 4; ++j) {
                    float e = __expf(pr[m][n][j] - normt[n]) * SCALE_;
                    zp[n] += e * ksum_l[rl + j];
                    ee[half * 4 + j] = e;
                }
            }
            unsigned r0,r1,r2,r3,r4,r5,r6,r7;
            unsigned h01 = pk_hi2(ee[0], ee[1], r0, r1);
            unsigned h23 = pk_hi2(ee[2], ee[3], r2, r3);
            unsigned h45 = pk_hi2(ee[4], ee[5], r4, r5);
            unsigned h67 = pk_hi2(ee[6], ee[7], r6, r7);
            unsigned l01 = pk_tr2(ee[0]-__uint_as_float(r0), ee[1]-__uint_as_float(r1));
            unsigned l23 = pk_tr2(ee[2]-__uint_as_float(r2), ee[3]-__uint_as_float(r3));
            unsigned l45 = pk_tr2(ee[4]-__uint_as_float(r4), ee[5]-__uint_as_float(r5));
            unsigned l67 = pk_tr2(ee[6]-__uint_as_float(r6), ee[7]-__uint_as_float(r7));
            aph[n] = mkbf8(h01, h23, h45, h67);
            apl[n] = mkbf8(l01, l23, l45, l67);
        }
        bf16x8 bkh[4], bkl[4];
#pragma unroll
        for (int nd = 0; nd < 4; ++nd) {
            int d  = nd * 16 + l15;
            int rb = rs * 64 + W * 32 + q * 4;
            short4v a0 = *(const short4v*)&kvTh[d * 264 + rb];
            short4v a1 = *(const short4v*)&kvTh[d * 264 + rb + 16];
            short4v b0 = *(const short4v*)&kvTl[d * 264 + rb];
            short4v b1 = *(const short4v*)&kvTl[d * 264 + rb + 16];
            bf16x8 hv, lv;
            hv[0]=a0.x; hv[1]=a0.y; hv[2]=a0.z; hv[3]=a0.w; hv[4]=a1.x; hv[5]=a1.y; hv[6]=a1.z; hv[7]=a1.w;
            lv[0]=b0.x; lv[1]=b0.y; lv[2]=b0.z; lv[3]=b0.w; lv[4]=b1.x; lv[5]=b1.y; lv[6]=b1.z; lv[7]=b1.w;
            bkh[nd] = hv; bkl[nd] = lv;
        }
#pragma unroll
        for (int n = 0; n < 4; ++n)
#pragma unroll
            for (int nd = 0; nd < 4; ++nd) {
                oac[n][nd] = __builtin_amdgcn_mfma_f32_16x16x32_bf16(aph[n], bkh[nd], oac[n][nd], 0, 0, 0);
                oac[n][nd] = __builtin_amdgcn_mfma_f32_16x16x32_bf16(aph[n], bkl[nd], oac[n][nd], 0, 0, 0);
                oac[n][nd] = __builtin_amdgcn_mfma_f32_16x16x32_bf16(apl[n], bkh[nd], oac[n][nd], 0, 0, 0);
            }
    }
#pragma unroll
    for (int n = 0; n < 4; ++n) {   // z partials (sum over r-quadrants)
        float v = zp[n];
        v += __shfl_xor(v, 16);
        v += __shfl_xor(v, 32);
        if (q == 0) zb[rs * 64 + n * 16 + l15] = v;
    }
    __syncthreads();   // all kvT reads done -> red (alias) writable; zb visible

    // ---- sequential reduce over r-strips into red ----
#pragma unroll
    for (int p = 0; p < 4; ++p) {
        if (rs == p) {
#pragma unroll
            for (int n = 0; n < 4; ++n)
#pragma unroll
                for (int nd = 0; nd < 4; ++nd)
#pragma unroll
                    for (int j = 0; j < 4; ++j) {
                        int idx = (n * 16 + q * 4 + j) * 68 + nd * 16 + l15;
                        if (p == 0) red[idx] = oac[n][nd][j];
                        else        red[idx] += oac[n][nd][j];
                    }
        }
        __syncthreads();
    }

    // ---- epilogue: divide by z+eps, store ----
#pragma unroll
    for (int i = 0; i < 4; ++i) {
        int flat = i * 1024 + tid * 4;
        int tl = flat >> 6, d = flat & 63;
        float z = zb[tl] + zb[64 + tl] + zb[128 + tl] + zb[192 + tl] + EPS_;
        float rz = 1.f / z;
        float4 o = *(const float4*)&red[tl * 68 + d];
        o.x *= rz; o.y *= rz; o.z *= rz; o.w *= rz;
        *(float4*)&outg[(rowb + t0 + tl) * 64 + d] = o;
    }
}

// ============================================================
extern "C" void kernel_launch(void* const* d_in, const int* in_sizes, int n_in,
                              void* d_out, int out_size, void* d_ws, size_t ws_size,
                              hipStream_t stream)
{
    const float* q  = (const float*)d_in[0];
    const float* k  = (const float*)d_in[1];
    const float* v  = (const float*)d_in[2];
    const float* m  = (const float*)d_in[3];
    const float* W  = (const float*)d_in[4];
    float* out = (float*)d_out;

    char* ws = (char*)d_ws;
    h16*   wfg = (h16*)ws;                                   // 65536 B
    short* kvt = (short*)(ws + 65536);                       // 4325376 B
    float* ksf = (float*)(ws + 65536 + 4325376);             // 65536 B

    int split = 8;
    while (split > 1) {
        size_t need = 65536ull + 4325376ull + 65536ull
                    + (size_t)split * (4194304ull + 65536ull);
        if (need <= ws_size) break;
        split >>= 1;
    }
    float* kvp = (float*)(ws + 65536 + 4325376 + 65536);
    float* ksp = kvp + (size_t)split * (256 * 64 * BH_);
    int nch = (T_ / split) / 64;

    k_prep  <<<dim3(64),           dim3(256), 0, stream>>>(W, wfg);
    k_stage1<<<dim3(split, BH_),   dim3(256), 0, stream>>>(k, v, m, wfg, kvp, ksp, nch);
    k_reduce<<<dim3(8, BH_),       dim3(256), 0, stream>>>(kvp, ksp, kvt, ksf, split);
    k_stage2<<<dim3(T_ / 64, BH_), dim3(256), 0, stream>>>(q, wfg, kvt, ksf, out);
}